// Round 1
// baseline (205.470 us; speedup 1.0000x reference)
//
#include <hip/hip_runtime.h>

#define NS   128          // samples
#define D    8128         // feature dim
#define P    8128         // pairs = N*(N-1)/2
#define EPSV 1e-12f
#define TP   64
#define TQ   64
#define NT   127          // 8128 / 64

// ---------------- kernel 1: pair indices + inverse norms ----------------
// one block (256 thr) per pair p
__global__ void norms_kernel(const float* __restrict__ Sr, const float* __restrict__ Sf,
                             float* __restrict__ inv_nr, float* __restrict__ inv_nf,
                             int* __restrict__ pi, int* __restrict__ pj) {
    int p = blockIdx.x;

    // invert p -> (i, j) for tril_indices(N, k=-1) row-major order:
    // row i holds j = 0..i-1 starting at offset i*(i-1)/2
    int i = (int)((1.0f + sqrtf(8.0f * (float)p + 1.0f)) * 0.5f);
    while (i * (i - 1) / 2 > p) --i;
    while ((i + 1) * i / 2 <= p) ++i;
    int j = p - i * (i - 1) / 2;

    const float4* ri = (const float4*)(Sr + (size_t)i * D);
    const float4* rj = (const float4*)(Sr + (size_t)j * D);
    const float4* fi = (const float4*)(Sf + (size_t)i * D);
    const float4* fj = (const float4*)(Sf + (size_t)j * D);

    float sr = 0.f, sf = 0.f;
    for (int d = threadIdx.x; d < D / 4; d += 256) {
        float4 a = ri[d], b = rj[d];
        float dx = a.x - b.x, dy = a.y - b.y, dz = a.z - b.z, dw = a.w - b.w;
        sr += dx * dx + dy * dy + dz * dz + dw * dw;
        float4 c = fi[d], e = fj[d];
        dx = c.x - e.x; dy = c.y - e.y; dz = c.z - e.z; dw = c.w - e.w;
        sf += dx * dx + dy * dy + dz * dz + dw * dw;
    }
    #pragma unroll
    for (int off = 32; off > 0; off >>= 1) {
        sr += __shfl_down(sr, off, 64);
        sf += __shfl_down(sf, off, 64);
    }
    __shared__ float wr[4], wf[4];
    int wave = threadIdx.x >> 6;
    if ((threadIdx.x & 63) == 0) { wr[wave] = sr; wf[wave] = sf; }
    __syncthreads();
    if (threadIdx.x == 0) {
        float tr = wr[0] + wr[1] + wr[2] + wr[3];
        float tf = wf[0] + wf[1] + wf[2] + wf[3];
        inv_nr[p] = 1.0f / sqrtf(tr);
        inv_nf[p] = 1.0f / sqrtf(tf);
        pi[p] = i;
        pj[p] = j;
    }
}

// ---------------- kernel 2: tiled transposed-elementwise product ----------------
// grid (NT, NT); block 256. Tile TP x TQ of the (p,q) plane.
__global__ void tile_kernel(const float* __restrict__ Sr, const float* __restrict__ Sf,
                            const float* __restrict__ inv_nr, const float* __restrict__ inv_nf,
                            const int* __restrict__ pi, const int* __restrict__ pj,
                            float* __restrict__ partials) {
    __shared__ float Ft[TP][TQ + 1];   // F[p][q] = max(v_fake[p,q]/nf[p], eps)
    __shared__ float Rt[TQ][TP + 1];   // R[q][p] = max(v_real[q,p]/nr[q], eps)

    int p0 = blockIdx.x * TP;
    int q0 = blockIdx.y * TQ;
    int lq = threadIdx.x & 63;   // lane within wave: column index (coalesced)
    int l4 = threadIdx.x >> 6;   // wave id 0..3

    for (int pp = l4; pp < TP; pp += 4) {
        int p = p0 + pp;
        int ip = pi[p], jp = pj[p];
        float v = (Sf[(size_t)ip * D + q0 + lq] - Sf[(size_t)jp * D + q0 + lq]) * inv_nf[p];
        Ft[pp][lq] = fmaxf(v, EPSV);
    }
    for (int qq = l4; qq < TQ; qq += 4) {
        int q = q0 + qq;
        int iq = pi[q], jq = pj[q];
        float v = (Sr[(size_t)iq * D + p0 + lq] - Sr[(size_t)jq * D + p0 + lq]) * inv_nr[q];
        Rt[qq][lq] = fmaxf(v, EPSV);
    }
    __syncthreads();

    float acc = 0.f;
    #pragma unroll
    for (int pp = 0; pp < TP / 4; ++pp) {
        int prow = l4 + pp * 4;
        acc += Ft[prow][lq] * Rt[lq][prow];   // Rt stride 65: conflict-free
    }

    #pragma unroll
    for (int off = 32; off > 0; off >>= 1) acc += __shfl_down(acc, off, 64);
    __shared__ float wsum[4];
    if ((threadIdx.x & 63) == 0) wsum[l4] = acc;
    __syncthreads();
    if (threadIdx.x == 0)
        partials[blockIdx.y * NT + blockIdx.x] = wsum[0] + wsum[1] + wsum[2] + wsum[3];
}

// ---------------- kernel 3: final deterministic reduce ----------------
__global__ void reduce_kernel(const float* __restrict__ partials, int n, float* __restrict__ out) {
    float s = 0.f;
    for (int idx = threadIdx.x; idx < n; idx += 256) s += partials[idx];
    #pragma unroll
    for (int off = 32; off > 0; off >>= 1) s += __shfl_down(s, off, 64);
    __shared__ float w[4];
    int wave = threadIdx.x >> 6;
    if ((threadIdx.x & 63) == 0) w[wave] = s;
    __syncthreads();
    if (threadIdx.x == 0) out[0] = w[0] + w[1] + w[2] + w[3];
}

extern "C" void kernel_launch(void* const* d_in, const int* in_sizes, int n_in,
                              void* d_out, int out_size, void* d_ws, size_t ws_size,
                              hipStream_t stream) {
    const float* Sr = (const float*)d_in[0];   // S_real [128, 8128]
    const float* Sf = (const float*)d_in[1];   // S_fake [128, 8128]
    float* out = (float*)d_out;

    // workspace layout (all fp32/int32, ~190 KB total)
    float* inv_nr   = (float*)d_ws;
    float* inv_nf   = inv_nr + P;
    int*   pi       = (int*)(inv_nf + P);
    int*   pj       = pi + P;
    float* partials = (float*)(pj + P);

    norms_kernel<<<P, 256, 0, stream>>>(Sr, Sf, inv_nr, inv_nf, pi, pj);
    dim3 grid(NT, NT);
    tile_kernel<<<grid, 256, 0, stream>>>(Sr, Sf, inv_nr, inv_nf, pi, pj, partials);
    reduce_kernel<<<1, 256, 0, stream>>>(partials, NT * NT, out);
}

// Round 2
// 86.371 us; speedup vs baseline: 2.3789x; 2.3789x over previous
//
#include <hip/hip_runtime.h>

#define NS   128          // samples
#define D_   8128         // feature dim
#define P_   8128         // pairs
#define EPSV 1e-12f
#define NT   127          // 8128 / 64 tiles
#define KT   127          // gram k-tiles of 64

// ============ Gram path (fast norms): G = S * S^T per matrix ============
// grid (KT, 2), block 256. Each block: one 64-wide K-chunk, full 128x128 output.
__global__ void gram_partial(const float* __restrict__ Sr, const float* __restrict__ Sf,
                             float* __restrict__ Gpart) {
    int kc = blockIdx.x;         // 0..126
    int m  = blockIdx.y;         // 0 = real, 1 = fake
    const float* __restrict__ S = m ? Sf : Sr;
    float* __restrict__ out = Gpart + ((size_t)m * KT + kc) * (NS * NS);

    __shared__ float Slt[64][132];   // [k][i], pad 132 (mult of 4 -> aligned float4 reads)
    int t = threadIdx.x;

    // load chunk S[:, kc*64 .. +63] transposed: float4 along k, 4 scalar LDS writes
    #pragma unroll
    for (int s = 0; s < 8; ++s) {
        int e4  = t + 256 * s;           // 0..2047 float4s
        int row = e4 >> 4;               // 0..127
        int c4  = (e4 & 15) << 2;        // k offset 0,4,..,60
        const float4 v = *(const float4*)(S + (size_t)row * D_ + kc * 64 + c4);
        Slt[c4 + 0][row] = v.x;
        Slt[c4 + 1][row] = v.y;
        Slt[c4 + 2][row] = v.z;
        Slt[c4 + 3][row] = v.w;
    }
    __syncthreads();

    int i0 = (t >> 4) * 8, j0 = (t & 15) * 8;   // 8x8 entries per thread
    float acc[8][8];
    #pragma unroll
    for (int r = 0; r < 8; ++r)
        #pragma unroll
        for (int c = 0; c < 8; ++c) acc[r][c] = 0.f;

    #pragma unroll 4
    for (int k = 0; k < 64; ++k) {
        float4 a0 = *(const float4*)&Slt[k][i0];
        float4 a1 = *(const float4*)&Slt[k][i0 + 4];
        float4 b0 = *(const float4*)&Slt[k][j0];
        float4 b1 = *(const float4*)&Slt[k][j0 + 4];
        float a[8] = {a0.x, a0.y, a0.z, a0.w, a1.x, a1.y, a1.z, a1.w};
        float b[8] = {b0.x, b0.y, b0.z, b0.w, b1.x, b1.y, b1.z, b1.w};
        #pragma unroll
        for (int r = 0; r < 8; ++r)
            #pragma unroll
            for (int c = 0; c < 8; ++c) acc[r][c] += a[r] * b[c];
    }
    #pragma unroll
    for (int r = 0; r < 8; ++r) {
        *(float4*)&out[(i0 + r) * NS + j0]     = make_float4(acc[r][0], acc[r][1], acc[r][2], acc[r][3]);
        *(float4*)&out[(i0 + r) * NS + j0 + 4] = make_float4(acc[r][4], acc[r][5], acc[r][6], acc[r][7]);
    }
}

// grid 128, block 256: sum 127 partials per entry (2*16384 entries)
__global__ void gram_reduce(const float* __restrict__ Gpart, float* __restrict__ G) {
    int idx = blockIdx.x * 256 + threadIdx.x;      // 0..32767
    int m = idx >> 14, e = idx & 16383;
    const float* __restrict__ src = Gpart + (size_t)m * KT * (NS * NS) + e;
    float s = 0.f;
    for (int c = 0; c < KT; ++c) s += src[(size_t)c * (NS * NS)];
    G[idx] = s;
}

// grid 32, block 256: pair indices + inverse norms from Gram
__global__ void pairnorm(const float* __restrict__ G,
                         float* __restrict__ inv_nr, float* __restrict__ inv_nf,
                         int* __restrict__ pi, int* __restrict__ pj) {
    int p = blockIdx.x * 256 + threadIdx.x;
    if (p >= P_) return;
    int i = (int)((1.0f + sqrtf(8.0f * (float)p + 1.0f)) * 0.5f);
    while (i * (i - 1) / 2 > p) --i;
    while ((i + 1) * i / 2 <= p) ++i;
    int j = p - i * (i - 1) / 2;
    const float* Gr = G;
    const float* Gf = G + NS * NS;
    float nr2 = Gr[i * NS + i] + Gr[j * NS + j] - 2.f * Gr[i * NS + j];
    float nf2 = Gf[i * NS + i] + Gf[j * NS + j] - 2.f * Gf[i * NS + j];
    inv_nr[p] = rsqrtf(nr2);
    inv_nf[p] = rsqrtf(nf2);
    pi[p] = i;
    pj[p] = j;
}

// ============ Fallback norms (round-1 proven, used if ws too small) ============
__global__ void norms_kernel(const float* __restrict__ Sr, const float* __restrict__ Sf,
                             float* __restrict__ inv_nr, float* __restrict__ inv_nf,
                             int* __restrict__ pi, int* __restrict__ pj) {
    int p = blockIdx.x;
    int i = (int)((1.0f + sqrtf(8.0f * (float)p + 1.0f)) * 0.5f);
    while (i * (i - 1) / 2 > p) --i;
    while ((i + 1) * i / 2 <= p) ++i;
    int j = p - i * (i - 1) / 2;

    const float4* ri = (const float4*)(Sr + (size_t)i * D_);
    const float4* rj = (const float4*)(Sr + (size_t)j * D_);
    const float4* fi = (const float4*)(Sf + (size_t)i * D_);
    const float4* fj = (const float4*)(Sf + (size_t)j * D_);

    float sr = 0.f, sf = 0.f;
    for (int d = threadIdx.x; d < D_ / 4; d += 256) {
        float4 a = ri[d], b = rj[d];
        float dx = a.x - b.x, dy = a.y - b.y, dz = a.z - b.z, dw = a.w - b.w;
        sr += dx * dx + dy * dy + dz * dz + dw * dw;
        float4 c = fi[d], e = fj[d];
        dx = c.x - e.x; dy = c.y - e.y; dz = c.z - e.z; dw = c.w - e.w;
        sf += dx * dx + dy * dy + dz * dz + dw * dw;
    }
    #pragma unroll
    for (int off = 32; off > 0; off >>= 1) {
        sr += __shfl_down(sr, off, 64);
        sf += __shfl_down(sf, off, 64);
    }
    __shared__ float wr[4], wf[4];
    int wave = threadIdx.x >> 6;
    if ((threadIdx.x & 63) == 0) { wr[wave] = sr; wf[wave] = sf; }
    __syncthreads();
    if (threadIdx.x == 0) {
        inv_nr[p] = 1.0f / sqrtf(wr[0] + wr[1] + wr[2] + wr[3]);
        inv_nf[p] = 1.0f / sqrtf(wf[0] + wf[1] + wf[2] + wf[3]);
        pi[p] = i;
        pj[p] = j;
    }
}

// ============ tile kernel v2: Rt-only LDS, inline F, scalarized row bases ============
// grid (NT, NT), block 256, 8 blocks/CU (LDS 16.7 KB) -> 100% occupancy
__global__ void __launch_bounds__(256, 8)
tile2_kernel(const float* __restrict__ Sr, const float* __restrict__ Sf,
             const float* __restrict__ inv_nr, const float* __restrict__ inv_nf,
             const int* __restrict__ pi, const int* __restrict__ pj,
             float* __restrict__ partials) {
    __shared__ float Rt[64][65];   // [q][p], stride 65: 2-way (free) on both write & transposed read
    int t  = threadIdx.x;
    int p0 = blockIdx.x * 64, q0 = blockIdx.y * 64;

    // ---- stage Rt: float4 loads along p, 4 scalar LDS writes
    int c  = t & 15;          // float4 col group
    int qr = t >> 4;          // 16 q-rows per pass
    #pragma unroll
    for (int pass = 0; pass < 4; ++pass) {
        int qq = qr + 16 * pass;
        int q  = q0 + qq;
        int iq = pi[q], jq = pj[q];
        float invr = inv_nr[q];
        const float4 a = *(const float4*)(Sr + (size_t)iq * D_ + p0 + 4 * c);
        const float4 b = *(const float4*)(Sr + (size_t)jq * D_ + p0 + 4 * c);
        Rt[qq][4 * c + 0] = fmaxf((a.x - b.x) * invr, EPSV);
        Rt[qq][4 * c + 1] = fmaxf((a.y - b.y) * invr, EPSV);
        Rt[qq][4 * c + 2] = fmaxf((a.z - b.z) * invr, EPSV);
        Rt[qq][4 * c + 3] = fmaxf((a.w - b.w) * invr, EPSV);
    }
    __syncthreads();

    // ---- compute: wave w owns p-rows {w, w+4, ..., w+60}; F computed inline
    int lq = t & 63, w = t >> 6;
    int qcol = q0 + lq;
    float acc = 0.f;
    #pragma unroll
    for (int it = 0; it < 16; ++it) {
        int prow = w + 4 * it;
        int p = __builtin_amdgcn_readfirstlane(p0 + prow);   // wave-uniform -> scalar loads
        int ip = pi[p], jp = pj[p];
        float invf = inv_nf[p];
        float fa = Sf[(size_t)ip * D_ + qcol];
        float fb = Sf[(size_t)jp * D_ + qcol];
        float f = fmaxf((fa - fb) * invf, EPSV);
        acc += f * Rt[lq][prow];
    }

    #pragma unroll
    for (int off = 32; off > 0; off >>= 1) acc += __shfl_down(acc, off, 64);
    __shared__ float wsum[4];
    if (lq == 0) wsum[w] = acc;
    __syncthreads();
    if (t == 0) partials[blockIdx.y * NT + blockIdx.x] = wsum[0] + wsum[1] + wsum[2] + wsum[3];
}

// ============ final deterministic reduce ============
__global__ void reduce_kernel(const float* __restrict__ partials, int n, float* __restrict__ out) {
    float s = 0.f;
    for (int idx = threadIdx.x; idx < n; idx += 256) s += partials[idx];
    #pragma unroll
    for (int off = 32; off > 0; off >>= 1) s += __shfl_down(s, off, 64);
    __shared__ float wbuf[4];
    int wave = threadIdx.x >> 6;
    if ((threadIdx.x & 63) == 0) wbuf[wave] = s;
    __syncthreads();
    if (threadIdx.x == 0) out[0] = wbuf[0] + wbuf[1] + wbuf[2] + wbuf[3];
}

extern "C" void kernel_launch(void* const* d_in, const int* in_sizes, int n_in,
                              void* d_out, int out_size, void* d_ws, size_t ws_size,
                              hipStream_t stream) {
    const float* Sr = (const float*)d_in[0];
    const float* Sf = (const float*)d_in[1];
    float* out = (float*)d_out;

    // ws layout (floats)
    float* inv_nr = (float*)d_ws;                     // P
    float* inv_nf = inv_nr + P_;                      // P
    int*   pi     = (int*)(inv_nf + P_);              // P
    int*   pj     = pi + P_;                          // P
    float* tpart  = (float*)(pj + P_);                // NT*NT
    float* G      = tpart + NT * NT;                  // 2*128*128
    float* Gpart  = G + 2 * NS * NS;                  // 2*KT*128*128

    size_t need = ((size_t)4 * P_ + (size_t)NT * NT + 2 * NS * NS
                   + (size_t)2 * KT * NS * NS) * sizeof(float);

    if (ws_size >= need) {
        dim3 gg(KT, 2);
        gram_partial<<<gg, 256, 0, stream>>>(Sr, Sf, Gpart);
        gram_reduce<<<128, 256, 0, stream>>>(Gpart, G);
        pairnorm<<<32, 256, 0, stream>>>(G, inv_nr, inv_nf, pi, pj);
    } else {
        norms_kernel<<<P_, 256, 0, stream>>>(Sr, Sf, inv_nr, inv_nf, pi, pj);
    }

    dim3 grid(NT, NT);
    tile2_kernel<<<grid, 256, 0, stream>>>(Sr, Sf, inv_nr, inv_nf, pi, pj, tpart);
    reduce_kernel<<<1, 256, 0, stream>>>(tpart, NT * NT, out);
}

// Round 3
// 83.482 us; speedup vs baseline: 2.4612x; 1.0346x over previous
//
#include <hip/hip_runtime.h>

#define NS   128          // samples
#define D_   8128         // feature dim
#define P_   8128         // pairs
#define EPSV 1e-12f
#define NT   127          // 8128 / 64 tiles
#define KT   127          // gram k-chunks of 64

// ============ Gram path: G = S * S^T per matrix, split-K partials ============
// grid (KT, 2, 2), block 256. Block: one 64-wide K-chunk, one matrix, one
// 64-row slab of the 128x128 output. Per-thread 8x4 (32 acc regs, no spill).
__global__ void __launch_bounds__(256, 2)
gram_partial(const float* __restrict__ Sr, const float* __restrict__ Sf,
             float* __restrict__ Gpart) {
    int kc = blockIdx.x;         // 0..126
    int m  = blockIdx.y;         // 0 = real, 1 = fake
    int sl = blockIdx.z;         // row slab 0/1
    const float* __restrict__ S = m ? Sf : Sr;
    float* __restrict__ out = Gpart + ((size_t)m * KT + kc) * (NS * NS);

    __shared__ float Slt[64][132];   // [k][i] transposed chunk
    int t = threadIdx.x;

    #pragma unroll
    for (int s = 0; s < 8; ++s) {
        int e4  = t + 256 * s;           // 0..2047 float4s
        int row = e4 >> 4;               // 0..127
        int c4  = (e4 & 15) << 2;        // k offset 0,4,..,60
        const float4 v = *(const float4*)(S + (size_t)row * D_ + kc * 64 + c4);
        Slt[c4 + 0][row] = v.x;
        Slt[c4 + 1][row] = v.y;
        Slt[c4 + 2][row] = v.z;
        Slt[c4 + 3][row] = v.w;
    }
    __syncthreads();

    int i0 = sl * 64 + (t >> 5) * 8;     // 8 rows
    int j0 = (t & 31) * 4;               // 4 cols
    float acc[8][4];
    #pragma unroll
    for (int r = 0; r < 8; ++r)
        #pragma unroll
        for (int c = 0; c < 4; ++c) acc[r][c] = 0.f;

    #pragma unroll 4
    for (int k = 0; k < 64; ++k) {
        float4 a0 = *(const float4*)&Slt[k][i0];
        float4 a1 = *(const float4*)&Slt[k][i0 + 4];
        float4 b  = *(const float4*)&Slt[k][j0];
        float a[8] = {a0.x, a0.y, a0.z, a0.w, a1.x, a1.y, a1.z, a1.w};
        #pragma unroll
        for (int r = 0; r < 8; ++r) {
            acc[r][0] += a[r] * b.x;
            acc[r][1] += a[r] * b.y;
            acc[r][2] += a[r] * b.z;
            acc[r][3] += a[r] * b.w;
        }
    }
    #pragma unroll
    for (int r = 0; r < 8; ++r)
        *(float4*)&out[(i0 + r) * NS + j0] =
            make_float4(acc[r][0], acc[r][1], acc[r][2], acc[r][3]);
}

// grid 128, block 256: sum 127 chunk-partials per entry (coalesced per step)
__global__ void gram_reduce(const float* __restrict__ Gpart, float* __restrict__ G) {
    int idx = blockIdx.x * 256 + threadIdx.x;      // 0..32767
    int m = idx >> 14, e = idx & 16383;
    const float* __restrict__ src = Gpart + (size_t)m * KT * (NS * NS) + e;
    float s = 0.f;
    for (int c = 0; c < KT; ++c) s += src[(size_t)c * (NS * NS)];
    G[idx] = s;
}

// grid 32, block 256: pair row-offsets + inverse norms from Gram
__global__ void pairnorm(const float* __restrict__ G,
                         float* __restrict__ inv_nr, float* __restrict__ inv_nf,
                         int* __restrict__ opi, int* __restrict__ opj) {
    int p = blockIdx.x * 256 + threadIdx.x;
    if (p >= P_) return;
    int i = (int)((1.0f + sqrtf(8.0f * (float)p + 1.0f)) * 0.5f);
    while (i * (i - 1) / 2 > p) --i;
    while ((i + 1) * i / 2 <= p) ++i;
    int j = p - i * (i - 1) / 2;
    const float* Gr = G;
    const float* Gf = G + NS * NS;
    float nr2 = Gr[i * NS + i] + Gr[j * NS + j] - 2.f * Gr[i * NS + j];
    float nf2 = Gf[i * NS + i] + Gf[j * NS + j] - 2.f * Gf[i * NS + j];
    inv_nr[p] = rsqrtf(nr2);
    inv_nf[p] = rsqrtf(nf2);
    opi[p] = i * D_;        // element offset of row i
    opj[p] = j * D_;
}

// ============ Fallback norms (used only if ws too small) ============
__global__ void norms_kernel(const float* __restrict__ Sr, const float* __restrict__ Sf,
                             float* __restrict__ inv_nr, float* __restrict__ inv_nf,
                             int* __restrict__ opi, int* __restrict__ opj) {
    int p = blockIdx.x;
    int i = (int)((1.0f + sqrtf(8.0f * (float)p + 1.0f)) * 0.5f);
    while (i * (i - 1) / 2 > p) --i;
    while ((i + 1) * i / 2 <= p) ++i;
    int j = p - i * (i - 1) / 2;

    const float4* ri = (const float4*)(Sr + (size_t)i * D_);
    const float4* rj = (const float4*)(Sr + (size_t)j * D_);
    const float4* fi = (const float4*)(Sf + (size_t)i * D_);
    const float4* fj = (const float4*)(Sf + (size_t)j * D_);

    float sr = 0.f, sf = 0.f;
    for (int d = threadIdx.x; d < D_ / 4; d += 256) {
        float4 a = ri[d], b = rj[d];
        float dx = a.x - b.x, dy = a.y - b.y, dz = a.z - b.z, dw = a.w - b.w;
        sr += dx * dx + dy * dy + dz * dz + dw * dw;
        float4 c = fi[d], e = fj[d];
        dx = c.x - e.x; dy = c.y - e.y; dz = c.z - e.z; dw = c.w - e.w;
        sf += dx * dx + dy * dy + dz * dz + dw * dw;
    }
    #pragma unroll
    for (int off = 32; off > 0; off >>= 1) {
        sr += __shfl_down(sr, off, 64);
        sf += __shfl_down(sf, off, 64);
    }
    __shared__ float wr[4], wf[4];
    int wave = threadIdx.x >> 6;
    if ((threadIdx.x & 63) == 0) { wr[wave] = sr; wf[wave] = sf; }
    __syncthreads();
    if (threadIdx.x == 0) {
        inv_nr[p] = 1.0f / sqrtf(wr[0] + wr[1] + wr[2] + wr[3]);
        inv_nf[p] = 1.0f / sqrtf(wf[0] + wf[1] + wf[2] + wf[3]);
        opi[p] = i * D_;
        opj[p] = j * D_;
    }
}

// ============ tile kernel v3: float4 F-loads, transposed Rt, LDS p-metadata ====
// grid (NT, NT), block 256. Per-thread 4 prow x 4 qcol with float4 everywhere.
__global__ void __launch_bounds__(256, 6)
tile3_kernel(const float* __restrict__ Sr, const float* __restrict__ Sf,
             const float* __restrict__ inv_nr, const float* __restrict__ inv_nf,
             const int* __restrict__ opi, const int* __restrict__ opj,
             float* __restrict__ partials) {
    __shared__ float Rt[64][65];   // [p][q]: Rt[pp][qq] = R[q0+qq][p0+pp]
    __shared__ int   sIp[64], sJp[64];
    __shared__ float sInvF[64];
    __shared__ float wsum[4];

    int t  = threadIdx.x;
    int p0 = blockIdx.x * 64, q0 = blockIdx.y * 64;

    // p-row metadata for the compute phase
    if (t < 64) {
        int p = p0 + t;
        sIp[t]   = opi[p];
        sJp[t]   = opj[p];
        sInvF[t] = inv_nf[p];
    }

    // ---- stage Rt (transposed): float4 loads along p, 4 scalar LDS writes
    {
        int c  = t & 15;          // float4 col group along p
        int qr = t >> 4;          // q-row base
        #pragma unroll
        for (int pass = 0; pass < 4; ++pass) {
            int qq = qr + 16 * pass;
            int q  = q0 + qq;
            int oi = opi[q], oj = opj[q];
            float invr = inv_nr[q];
            const float4 a = *(const float4*)(Sr + oi + p0 + 4 * c);
            const float4 b = *(const float4*)(Sr + oj + p0 + 4 * c);
            Rt[4 * c + 0][qq] = fmaxf((a.x - b.x) * invr, EPSV);
            Rt[4 * c + 1][qq] = fmaxf((a.y - b.y) * invr, EPSV);
            Rt[4 * c + 2][qq] = fmaxf((a.z - b.z) * invr, EPSV);
            Rt[4 * c + 3][qq] = fmaxf((a.w - b.w) * invr, EPSV);
        }
    }
    __syncthreads();

    // ---- compute: thread owns 4 prows x 4 qcols, all loads are b128
    int qg = t & 15;              // qcols q0 + 4*qg .. +3
    int pg = t >> 4;
    float ax = 0.f, ay = 0.f, az = 0.f, aw = 0.f;
    #pragma unroll
    for (int pp = 0; pp < 4; ++pp) {
        int prow = pg + 16 * pp;
        int oi = sIp[prow], oj = sJp[prow];
        float invf = sInvF[prow];
        const float4 fa = *(const float4*)(Sf + oi + q0 + 4 * qg);
        const float4 fb = *(const float4*)(Sf + oj + q0 + 4 * qg);
        const float4 r  = *(const float4*)&Rt[prow][4 * qg];
        ax += fmaxf((fa.x - fb.x) * invf, EPSV) * r.x;
        ay += fmaxf((fa.y - fb.y) * invf, EPSV) * r.y;
        az += fmaxf((fa.z - fb.z) * invf, EPSV) * r.z;
        aw += fmaxf((fa.w - fb.w) * invf, EPSV) * r.w;
    }
    float acc = (ax + ay) + (az + aw);

    #pragma unroll
    for (int off = 32; off > 0; off >>= 1) acc += __shfl_down(acc, off, 64);
    int w = t >> 6;
    if ((t & 63) == 0) wsum[w] = acc;
    __syncthreads();
    if (t == 0) partials[blockIdx.y * NT + blockIdx.x] = wsum[0] + wsum[1] + wsum[2] + wsum[3];
}

// ============ final deterministic reduce ============
__global__ void reduce_kernel(const float* __restrict__ partials, int n, float* __restrict__ out) {
    float s = 0.f;
    for (int idx = threadIdx.x; idx < n; idx += 256) s += partials[idx];
    #pragma unroll
    for (int off = 32; off > 0; off >>= 1) s += __shfl_down(s, off, 64);
    __shared__ float wbuf[4];
    int wave = threadIdx.x >> 6;
    if ((threadIdx.x & 63) == 0) wbuf[wave] = s;
    __syncthreads();
    if (threadIdx.x == 0) out[0] = wbuf[0] + wbuf[1] + wbuf[2] + wbuf[3];
}

extern "C" void kernel_launch(void* const* d_in, const int* in_sizes, int n_in,
                              void* d_out, int out_size, void* d_ws, size_t ws_size,
                              hipStream_t stream) {
    const float* Sr = (const float*)d_in[0];
    const float* Sf = (const float*)d_in[1];
    float* out = (float*)d_out;

    // ws layout (floats)
    float* inv_nr = (float*)d_ws;                     // P
    float* inv_nf = inv_nr + P_;                      // P
    int*   opi    = (int*)(inv_nf + P_);              // P
    int*   opj    = opi + P_;                         // P
    float* tpart  = (float*)(opj + P_);               // NT*NT
    float* G      = tpart + NT * NT;                  // 2*128*128
    float* Gpart  = G + 2 * NS * NS;                  // 2*KT*128*128

    size_t need = ((size_t)4 * P_ + (size_t)NT * NT + 2 * NS * NS
                   + (size_t)2 * KT * NS * NS) * sizeof(float);

    if (ws_size >= need) {
        dim3 gg(KT, 2, 2);
        gram_partial<<<gg, 256, 0, stream>>>(Sr, Sf, Gpart);
        gram_reduce<<<128, 256, 0, stream>>>(Gpart, G);
        pairnorm<<<32, 256, 0, stream>>>(G, inv_nr, inv_nf, opi, opj);
    } else {
        norms_kernel<<<P_, 256, 0, stream>>>(Sr, Sf, inv_nr, inv_nf, opi, opj);
    }

    dim3 grid(NT, NT);
    tile3_kernel<<<grid, 256, 0, stream>>>(Sr, Sf, inv_nr, inv_nf, opi, opj, tpart);
    reduce_kernel<<<1, 256, 0, stream>>>(tpart, NT * NT, out);
}